// Round 15
// baseline (133.531 us; speedup 1.0000x reference)
//
#include <hip/hip_runtime.h>
#include <hip/hip_bf16.h>

typedef unsigned int u32;
typedef unsigned char u8;
typedef _Float16 f16;
typedef f16 f16x2 __attribute__((ext_vector_type(2)));
typedef short s16x8 __attribute__((ext_vector_type(8)));
typedef float f32x4 __attribute__((ext_vector_type(4)));

#define BB 64
#define LL 128
#define TT 64
#define NN 128
#define NM (NN*NN)   // 16384

__device__ __forceinline__ float sigf(float v) {
    return 1.0f / (1.0f + __expf(-v));
}

__device__ __forceinline__ float clip01(float v) {
    return fminf(fmaxf(v, 0.f), 1.f);
}

__device__ __forceinline__ u32 f2bf(float f) {   // f32 -> bf16 bits (RNE)
    u32 u = __builtin_bit_cast(u32, f);
    return (u + 0x7fffu + ((u >> 16) & 1u)) >> 16;
}

__device__ __forceinline__ float fdot2f(f16x2 wa, f16x2 xa, float ca) {
#if defined(__HIP_DEVICE_COMPILE__) && __has_builtin(__builtin_amdgcn_fdot2)
    return __builtin_amdgcn_fdot2(wa, xa, ca, false);
#else
    return ca + (float)wa[0] * (float)xa[0] + (float)wa[1] * (float)xa[1];
#endif
}

__device__ __forceinline__ u32 ud4(u32 a, u32 b, u32 c) {   // 4x u8 dot + acc
#if defined(__HIP_DEVICE_COMPILE__) && __has_builtin(__builtin_amdgcn_udot4)
    return __builtin_amdgcn_udot4(a, b, c, false);
#else
    return c + (a & 255u) * (b & 255u) + ((a >> 8) & 255u) * ((b >> 8) & 255u)
             + ((a >> 16) & 255u) * ((b >> 16) & 255u) + (a >> 24) * (b >> 24);
#endif
}

// ---------------------------------------------------------------------------
// pack_wx: merged pack_w (bid<512) + pack_x (bid>=512). Block 0 also zeroes
// the producer/consumer flags (kernel boundary flushes before mega launch).
__global__ __launch_bounds__(256) void pack_wx(const float* __restrict__ ntp,
                                               const float* __restrict__ x_all,
                                               ushort* __restrict__ wpk,
                                               ushort* __restrict__ xpk,
                                               u32* __restrict__ flags) {
    const int bid = blockIdx.x;
    if (bid == 0 && threadIdx.x < 128) flags[threadIdx.x] = 0u;
    if (bid < 512) {
        const int g = bid * 256 + threadIdx.x;   // 0..131071
        const int l = g & 63, h = (g >> 6) & 1, i = g >> 7;
        const int row = i * 16 + (l & 15);
        const int t0 = h * 32 + ((l >> 4) << 3);
        const float* src = ntp + row * 64 + t0;
        float4 f0 = *reinterpret_cast<const float4*>(src);
        float4 f1 = *reinterpret_cast<const float4*>(src + 4);
        float v[8] = {f0.x, f0.y, f0.z, f0.w, f1.x, f1.y, f1.z, f1.w};
        u32 o[4];
        #pragma unroll
        for (int q = 0; q < 4; ++q)
            o[q] = f2bf(sigf(v[2 * q])) | (f2bf(sigf(v[2 * q + 1])) << 16);
        uint4 ov; ov.x = o[0]; ov.y = o[1]; ov.z = o[2]; ov.w = o[3];
        *reinterpret_cast<uint4*>(wpk + (size_t)g * 8) = ov;
    } else {
        const int g = (bid - 512) * 256 + threadIdx.x;   // 0..65535
        const int l = g & 63, h = (g >> 6) & 1, j = (g >> 7) & 7, b = g >> 10;
        const int s = j * 16 + (l & 15);
        const int t0 = h * 32 + ((l >> 4) << 3);
        const float* src = x_all + ((size_t)b * LL + s) * TT + t0;
        float4 f0 = *reinterpret_cast<const float4*>(src);
        float4 f1 = *reinterpret_cast<const float4*>(src + 4);
        float v[8] = {f0.x, f0.y, f0.z, f0.w, f1.x, f1.y, f1.z, f1.w};
        u32 o[4];
        #pragma unroll
        for (int q = 0; q < 4; ++q)
            o[q] = f2bf(v[2 * q]) | (f2bf(v[2 * q + 1]) << 16);
        uint4 ov; ov.x = o[0]; ov.y = o[1]; ov.z = o[2]; ov.w = o[3];
        *reinterpret_cast<uint4*>(xpk + (size_t)g * 8) = ov;
    }
}

// ---------------------------------------------------------------------------
// mega: fused producer/consumer.
//   bid <  1024: GEMM role. jh = bid>>9 selects s-half (j in [4jh,4jh+4));
//                b = (bid&511)>>3, nb8 = bid&7 -> nb in {2nb8, 2nb8+1}.
//                Layout R4 (u4): npc byte(b,s,n,m) = b<<20 | (s>>4)<<17
//                | (s&15)<<13 | ((m>>4)+8*(n>>6))<<9 | (n&63)<<3 | (m&15)>>1.
//                On completion: vmcnt(0), syncthreads, threadfence,
//                atomicAdd(flags[b*2+jh]) (8 producers per flag).
//   bid >= 1024: RECUR role (round-13 recur9, 4 waves). Polls flags[2b]==8
//                before first load, flags[2b+1]==8 before prefetching s>=64.
__global__ __launch_bounds__(256, 1) void mega(const float* __restrict__ x_all,
                                               const float* __restrict__ tp,
                                               const ushort* __restrict__ wpk,
                                               const ushort* __restrict__ xpk,
                                               u8* __restrict__ npc,
                                               u32* __restrict__ flags,
                                               float* __restrict__ outp) {
    __shared__ __align__(16) u8 stg[4][4096];     // gemm staging (16 KB)
    __shared__ u32 prev_pk[2][32];                // recur state
    __shared__ float masks_lds[LL];
    __shared__ float tpc_lds[NN];
    __shared__ float x0_lds[TT];

    const int bid = blockIdx.x;
    const int tid = threadIdx.x;

    if (bid < 1024) {
        // ===================== GEMM role =====================
        const int jh  = bid >> 9;
        const int rem = bid & 511;
        const int b   = rem >> 3;
        const int nb8 = rem & 7;
        const int wv = tid >> 6, l = tid & 63;

        uint4 xf[4][2];
        #pragma unroll
        for (int jl = 0; jl < 4; ++jl)
            #pragma unroll
            for (int h = 0; h < 2; ++h)
                xf[jl][h] = *reinterpret_cast<const uint4*>(
                    xpk + (size_t)(((b * 8 + (jh * 4 + jl)) * 2 + h) * 64 + l) * 8);

        const int c = l & 15, r0 = (l >> 4) * 4;
        u8* stw = stg[wv];

        for (int nh = 0; nh < 2; ++nh) {
            const int nb = nb8 * 2 + nh;
            const int khi  = (nb >> 3) * 8;
            const int nlow = (nb & 7) * 8;
            for (int mg2 = 0; mg2 < 2; ++mg2) {
                const int mg = wv * 2 + mg2;
                #pragma unroll
                for (int n_l = 0; n_l < 8; ++n_l) {
                    const int i = (nb * 8 + n_l) * 8 + mg;   // tile index
                    uint4 a0 = *reinterpret_cast<const uint4*>(wpk + (size_t)((i * 2 + 0) * 64 + l) * 8);
                    uint4 a1 = *reinterpret_cast<const uint4*>(wpk + (size_t)((i * 2 + 1) * 64 + l) * 8);
                    const f32x4 z = {0.f, 0.f, 0.f, 0.f};
                    f32x4 acc[4];
                    #pragma unroll
                    for (int jl = 0; jl < 4; ++jl)
                        acc[jl] = __builtin_amdgcn_mfma_f32_16x16x32_bf16(
                            __builtin_bit_cast(s16x8, a0), __builtin_bit_cast(s16x8, xf[jl][0]), z, 0, 0, 0);
                    #pragma unroll
                    for (int jl = 0; jl < 4; ++jl)
                        acc[jl] = __builtin_amdgcn_mfma_f32_16x16x32_bf16(
                            __builtin_bit_cast(s16x8, a1), __builtin_bit_cast(s16x8, xf[jl][1]), acc[jl], 0, 0, 0);

                    const int sk8 = ((n_l + c) & 7) << 3;   // skewed 8B slot
                    #pragma unroll
                    for (int jl = 0; jl < 4; ++jl) {
                        u32 q0 = (u32)(clip01(acc[jl][0]) * 15.f + 0.5f);
                        u32 q1 = (u32)(clip01(acc[jl][1]) * 15.f + 0.5f);
                        u32 q2 = (u32)(clip01(acc[jl][2]) * 15.f + 0.5f);
                        u32 q3 = (u32)(clip01(acc[jl][3]) * 15.f + 0.5f);
                        u32 hw = (q0 | (q1 << 4)) | ((q2 | (q3 << 4)) << 8);
                        *reinterpret_cast<ushort*>(stw + jl * 1024 + c * 64 + sk8 + (r0 >> 1)) = (ushort)hw;
                    }
                }
                asm volatile("s_waitcnt lgkmcnt(0)" ::: "memory");
                __builtin_amdgcn_sched_barrier(0);

                // flush: 4 j x 2 rounds of 64B full-line coalesced dwordx2
                #pragma unroll
                for (int jl = 0; jl < 4; ++jl) {
                    #pragma unroll
                    for (int r = 0; r < 2; ++r) {
                        const int slot = r * 64 + l;
                        const int cc = slot >> 3;        // s-index 0..15
                        const int nr = slot & 7;
                        uint2 v = *reinterpret_cast<const uint2*>(
                            stw + jl * 1024 + cc * 64 + (((nr + cc) & 7) << 3));
                        *reinterpret_cast<uint2*>(npc + ((size_t)b << 20)
                            + ((size_t)(jh * 4 + jl) << 17)
                            + ((size_t)cc << 13) + ((size_t)(mg + khi) << 9)
                            + ((nlow + nr) << 3)) = v;
                    }
                }
                asm volatile("s_waitcnt lgkmcnt(0)" ::: "memory");
                __builtin_amdgcn_sched_barrier(0);
            }
        }

        // completion signal: drain stores, fence device-wide, bump flag
        asm volatile("s_waitcnt vmcnt(0)" ::: "memory");
        __syncthreads();
        if (tid == 0) {
            __threadfence();
            atomicAdd(&flags[b * 2 + jh], 1u);
        }
        return;
    }

    // ===================== RECUR role (recur9) =====================
    const int b = bid - 1024;
    const int n = tid >> 1, h = tid & 1;
    const u8* npcl = npc + ((size_t)b << 20)
                   + ((size_t)((n >> 6) * 8 + h * 4) << 9) + (u32)(n & 63) * 8;

    // wait for this batch's first s-half (steps 1..63)
    {
        u32* f = &flags[b * 2];
        int guard = 0;
        while (atomicAdd(f, 0u) < 8u && ++guard < (1 << 20))
            __builtin_amdgcn_s_sleep(8);
        __threadfence();
    }

    if (tid < 128) masks_lds[tid] = x_all[(size_t)b * 8192 + tid * 64 + 63];
    else if (tid < 192) x0_lds[tid - 128] = x_all[(size_t)b * 8192 + (tid - 128)];
    __syncthreads();

#define LOADSET(R, T) do { \
        int _t = (T) <= 127 ? (T) : 127; \
        const u8* _p = npcl + ((size_t)(_t >> 4) << 17) + ((size_t)(_t & 15) << 13); \
        R[0] = *reinterpret_cast<const uint2*>(_p); \
        R[1] = *reinterpret_cast<const uint2*>(_p + 512); \
        R[2] = *reinterpret_cast<const uint2*>(_p + 1024); \
        R[3] = *reinterpret_cast<const uint2*>(_p + 1536); \
        asm volatile("" ::: "memory"); \
    } while (0)

    uint2 nA[4], nB[4], nC[4], nD[4];
    LOADSET(nA, 1); LOADSET(nB, 2); LOADSET(nC, 3); LOADSET(nD, 4);

    // tpc (exact f32): thread tid < 128 computes row tid; hides prefetch
    float out_r = 0.f;
    if (tid < 128) {
        float a = 0.f;
        #pragma unroll
        for (int t4 = 0; t4 < 16; ++t4) {
            float4 xv = *reinterpret_cast<const float4*>(x0_lds + t4 * 4);
            float4 w0 = *reinterpret_cast<const float4*>(tp + tid * 64 + t4 * 4);
            a += sigf(w0.x) * xv.x; a += sigf(w0.y) * xv.y;
            a += sigf(w0.z) * xv.z; a += sigf(w0.w) * xv.w;
        }
        tpc_lds[tid] = a;
        if (tid == 0) out_r = a;            // out0 = tpc[0]
    }
    asm volatile("s_waitcnt lgkmcnt(0)" ::: "memory");
    __builtin_amdgcn_s_barrier();
    __builtin_amdgcn_sched_barrier(0);

    // packed-prev byte-write helper index for row n (h==0 threads)
    const int wr_idx  = ((n >> 4) << 1) + ((n >> 3) & 1) + ((n & 1) << 4);
    const int wr_byte = (n & 7) >> 1;

    // ---- step 1: cur1 = clip01(npc1 . tpc), tpc f32 (unclipped range) ----
    {
        float sf = 0.f;
        #pragma unroll
        for (int kk = 0; kk < 4; ++kk) {
            const int base_m = (4 * h + kk) * 16;
            u32 wlo = nA[kk].x, whi = nA[kk].y;
            #pragma unroll
            for (int by = 0; by < 4; ++by) {
                u32 b0 = (wlo >> (8 * by)) & 0xFFu;
                sf += (float)(b0 & 15u) * tpc_lds[base_m + 2 * by];
                sf += (float)(b0 >> 4)  * tpc_lds[base_m + 2 * by + 1];
                u32 b1 = (whi >> (8 * by)) & 0xFFu;
                sf += (float)(b1 & 15u) * tpc_lds[base_m + 8 + 2 * by];
                sf += (float)(b1 >> 4)  * tpc_lds[base_m + 8 + 2 * by + 1];
            }
        }
        float tot = sf + __shfl_xor(sf, 1);
        float c0 = clip01(tot * (1.f / 15.f));
        if (h == 0) {
            u32 q8 = (u32)(c0 * 255.f + 0.5f);
            ((u8*)&prev_pk[0][wr_idx])[wr_byte] = (u8)q8;
        }
        if (tid == 0) {
            float mk = masks_lds[1];
            out_r = out_r * mk + c0 * (1.f - mk);
        }
        asm volatile("s_waitcnt lgkmcnt(0)" ::: "memory");
        __builtin_amdgcn_s_barrier();
        __builtin_amdgcn_sched_barrier(0);
    }
    LOADSET(nA, 5);

    int p = 0;

#define STEP(R, S) do { \
        uint4 pe0 = *reinterpret_cast<const uint4*>(&prev_pk[p][8 * h]); \
        uint4 pe1 = *reinterpret_cast<const uint4*>(&prev_pk[p][8 * h + 4]); \
        uint4 po0 = *reinterpret_cast<const uint4*>(&prev_pk[p][16 + 8 * h]); \
        uint4 po1 = *reinterpret_cast<const uint4*>(&prev_pk[p][16 + 8 * h + 4]); \
        u32 PE[8] = {pe0.x, pe0.y, pe0.z, pe0.w, pe1.x, pe1.y, pe1.z, pe1.w}; \
        u32 PO[8] = {po0.x, po0.y, po0.z, po0.w, po1.x, po1.y, po1.z, po1.w}; \
        float mk = masks_lds[(S)]; \
        u32 ae = 0, ao = 0; \
        _Pragma("unroll") \
        for (int _kk = 0; _kk < 4; ++_kk) { \
            u32 _w0 = R[_kk].x, _w1 = R[_kk].y; \
            ae = ud4(_w0 & 0x0F0F0F0Fu, PE[2 * _kk], ae); \
            ao = ud4((_w0 >> 4) & 0x0F0F0F0Fu, PO[2 * _kk], ao); \
            ae = ud4(_w1 & 0x0F0F0F0Fu, PE[2 * _kk + 1], ae); \
            ao = ud4((_w1 >> 4) & 0x0F0F0F0Fu, PO[2 * _kk + 1], ao); \
        } \
        float sf = (float)(ae + ao); \
        float tot = sf + __shfl_xor(sf, 1); \
        float c0 = fminf(tot * (1.f / 3825.f), 1.f); \
        if (h == 0) { \
            u32 q8 = (u32)(c0 * 255.f + 0.5f); \
            ((u8*)&prev_pk[p ^ 1][wr_idx])[wr_byte] = (u8)q8; \
        } \
        if (tid == 0) out_r = out_r * mk + c0 * (1.f - mk); \
        asm volatile("s_waitcnt lgkmcnt(0)" ::: "memory"); \
        __builtin_amdgcn_s_barrier(); \
        __builtin_amdgcn_sched_barrier(0); \
        p ^= 1; \
    } while (0)

    // steps 2..57: g in [0,14) — all loads touch s < 64 only
    for (int g = 0; g < 14; ++g) {
        const int s = 2 + 4 * g;
        STEP(nB, s);     LOADSET(nB, s + 4);
        STEP(nC, s + 1); LOADSET(nC, s + 5);
        STEP(nD, s + 2); LOADSET(nD, s + 6);
        STEP(nA, s + 3); LOADSET(nA, s + 7);
    }
    // wait for second s-half (steps 64..127) before prefetching s >= 64
    {
        u32* f = &flags[b * 2 + 1];
        int guard = 0;
        while (atomicAdd(f, 0u) < 8u && ++guard < (1 << 20))
            __builtin_amdgcn_s_sleep(8);
        __threadfence();
    }
    // steps 58..125: g in [14,31)
    for (int g = 14; g < 31; ++g) {
        const int s = 2 + 4 * g;
        STEP(nB, s);     LOADSET(nB, s + 4);
        STEP(nC, s + 1); LOADSET(nC, s + 5);
        STEP(nD, s + 2); LOADSET(nD, s + 6);
        STEP(nA, s + 3); LOADSET(nA, s + 7);
    }
    // tail: steps 126 (nB), 127 (nC); nD/nA hold dead clamped loads
    STEP(nB, 126);
    STEP(nC, 127);

#undef STEP
#undef LOADSET

    if (tid == 0) outp[b] = out_r;
}

// ---------------------------------------------------------------------------
// Fallback (known-passing round-2 kernel): fused recurrence, 2 MB ws.
__global__ __launch_bounds__(256) void sig_transpose(const float* __restrict__ ntp,
                                                     u32* __restrict__ out) {
    __shared__ float lds[64 * 65];
    const int nm0 = blockIdx.x * 64;
    const int tid = threadIdx.x;
    #pragma unroll
    for (int it = 0; it < 16; ++it) {
        int idx = it * 256 + tid;
        int r = idx >> 6, c = idx & 63;
        lds[r * 65 + c] = sigf(ntp[(nm0 + r) * 64 + c]);
    }
    __syncthreads();
    #pragma unroll
    for (int it = 0; it < 8; ++it) {
        int o = it * 256 + tid;
        int tpi = o >> 6, r = o & 63;
        f16x2 h;
        h[0] = (f16)lds[r * 65 + 2 * tpi];
        h[1] = (f16)lds[r * 65 + 2 * tpi + 1];
        out[tpi * NM + nm0 + r] = __builtin_bit_cast(u32, h);
    }
}

__global__ __launch_bounds__(1024) void grammar_fused(
    const float* __restrict__ x_all,
    const float* __restrict__ tp,
    const u32*  __restrict__ ntpT2,
    float* __restrict__ outp) {
    __shared__ float x_lds[LL * TT];
    __shared__ float prevbuf[2][NN];
    __shared__ u32 x2_lds[2][32];

    const int b = blockIdx.x;
    const int tid = threadIdx.x;
    const int lane16 = tid & 15;
    const int g = tid >> 4;
    const int mbase = lane16 * 8;

    const float* xb = x_all + b * (LL * TT);
    #pragma unroll
    for (int it = 0; it < 8; ++it) {
        int idx = it * 1024 + tid;
        x_lds[idx] = xb[idx];
    }
    __syncthreads();

    if (tid < NN) {
        float acc = 0.f;
        #pragma unroll 8
        for (int t = 0; t < TT; ++t)
            acc += sigf(tp[tid * TT + t]) * x_lds[t];
        prevbuf[0][tid] = acc;
    }
    __syncthreads();
    float out_r = 0.f;
    if (tid == 0) out_r = prevbuf[0][0];

    int p = 0;
    for (int i0 = 1; i0 < LL; i0 += 2) {
        const int ns = (LL - i0) >= 2 ? 2 : 1;
        if (tid < 64) {
            int s = tid >> 5, tpi = tid & 31;
            f16x2 h;
            if (s < ns) {
                h[0] = (f16)x_lds[(i0 + s) * TT + 2 * tpi];
                h[1] = (f16)x_lds[(i0 + s) * TT + 2 * tpi + 1];
            } else {
                h[0] = (f16)0.f; h[1] = (f16)0.f;
            }
            x2_lds[s][tpi] = __builtin_bit_cast(u32, h);
        }
        __syncthreads();

        float acc[2][2][8];
        #pragma unroll
        for (int k = 0; k < 2; ++k)
            #pragma unroll
            for (int s = 0; s < 2; ++s)
                #pragma unroll
                for (int j = 0; j < 8; ++j) acc[k][s][j] = 0.f;

        #pragma unroll 2
        for (int tpi = 0; tpi < 32; ++tpi) {
            f16x2 xv0 = __builtin_bit_cast(f16x2, x2_lds[0][tpi]);
            f16x2 xv1 = __builtin_bit_cast(f16x2, x2_lds[1][tpi]);
            const u32* base = ntpT2 + tpi * NM + 8 * tid;
            #pragma unroll
            for (int k = 0; k < 2; ++k) {
                uint4 w0 = *reinterpret_cast<const uint4*>(base + 8192 * k);
                uint4 w1 = *reinterpret_cast<const uint4*>(base + 8192 * k + 4);
                u32 wv[8] = {w0.x, w0.y, w0.z, w0.w, w1.x, w1.y, w1.z, w1.w};
                #pragma unroll
                for (int j = 0; j < 8; ++j) {
                    f16x2 w = __builtin_bit_cast(f16x2, wv[j]);
                    acc[k][0][j] = fdot2f(w, xv0, acc[k][0][j]);
                    acc[k][1][j] = fdot2f(w, xv1, acc[k][1][j]);
                }
            }
        }

        for (int s = 0; s < ns; ++s) {
            float4 pv0 = *reinterpret_cast<const float4*>(&prevbuf[p][mbase]);
            float4 pv1 = *reinterpret_cast<const float4*>(&prevbuf[p][mbase + 4]);
            float pvv[8] = {pv0.x, pv0.y, pv0.z, pv0.w, pv1.x, pv1.y, pv1.z, pv1.w};
            #pragma unroll
            for (int k = 0; k < 2; ++k) {
                float part = 0.f;
                #pragma unroll
                for (int j = 0; j < 8; ++j) {
                    float npcv = clip01(acc[k][s][j]);
                    part += npcv * pvv[j];
                }
                part += __shfl_xor(part, 1);
                part += __shfl_xor(part, 2);
                part += __shfl_xor(part, 4);
                part += __shfl_xor(part, 8);
                if (lane16 == 0) {
                    float c = clip01(part);
                    prevbuf[p ^ 1][g + 64 * k] = c;
                    if (tid == 0 && k == 0) {
                        float mask = x_lds[(i0 + s) * TT + 63];
                        out_r = out_r * mask + c * (1.f - mask);
                    }
                }
            }
            p ^= 1;
            __syncthreads();
        }
    }

    if (tid == 0) outp[b] = out_r;
}

// ---------------------------------------------------------------------------
extern "C" void kernel_launch(void* const* d_in, const int* in_sizes, int n_in,
                              void* d_out, int out_size, void* d_ws, size_t ws_size,
                              hipStream_t stream) {
    const float* input_tensor = (const float*)d_in[0];   // [64][128][64]
    const float* term_prod    = (const float*)d_in[1];   // [128][64]
    const float* nonterm_prod = (const float*)d_in[2];   // [128][128][64]
    float* outp = (float*)d_out;                         // [64]

    const size_t MB = 1024 * 1024;
    const size_t NPC_BYTES = 64 * MB;    // layout R4 (u4)
    const size_t WPK_BYTES = 2 * MB;     // bf16 A-frags
    const size_t XPK_BYTES = 1 * MB;     // bf16 B-frags
    const size_t FLG_BYTES = 512;        // 128 u32 flags

    if (ws_size >= NPC_BYTES + WPK_BYTES + XPK_BYTES + FLG_BYTES + MB) {
        u8* npcbuf  = (u8*)d_ws;
        ushort* wpk = (ushort*)((char*)d_ws + NPC_BYTES);
        ushort* xpk = (ushort*)((char*)d_ws + NPC_BYTES + WPK_BYTES);
        u32* flags  = (u32*)((char*)d_ws + NPC_BYTES + WPK_BYTES + XPK_BYTES);
        pack_wx<<<768, 256, 0, stream>>>(nonterm_prod, input_tensor, wpk, xpk, flags);
        mega<<<1088, 256, 0, stream>>>(input_tensor, term_prod, wpk, xpk,
                                       npcbuf, flags, outp);
    } else {
        u32* ntpT2 = (u32*)d_ws;
        sig_transpose<<<256, 256, 0, stream>>>(nonterm_prod, ntpT2);
        grammar_fused<<<BB, 1024, 0, stream>>>(input_tensor, term_prod, ntpT2, outp);
    }
}

// Round 16
// 77.680 us; speedup vs baseline: 1.7190x; 1.7190x over previous
//
#include <hip/hip_runtime.h>
#include <hip/hip_bf16.h>

typedef unsigned int u32;
typedef unsigned char u8;
typedef _Float16 f16;
typedef f16 f16x2 __attribute__((ext_vector_type(2)));
typedef short s16x8 __attribute__((ext_vector_type(8)));
typedef float f32x4 __attribute__((ext_vector_type(4)));

#define BB 64
#define LL 128
#define TT 64
#define NN 128
#define NM (NN*NN)   // 16384

__device__ __forceinline__ float sigf(float v) {
    return 1.0f / (1.0f + __expf(-v));
}

__device__ __forceinline__ float clip01(float v) {
    return fminf(fmaxf(v, 0.f), 1.f);
}

__device__ __forceinline__ u32 f2bf(float f) {   // f32 -> bf16 bits (RNE)
    u32 u = __builtin_bit_cast(u32, f);
    return (u + 0x7fffu + ((u >> 16) & 1u)) >> 16;
}

__device__ __forceinline__ float fdot2f(f16x2 wa, f16x2 xa, float ca) {
#if defined(__HIP_DEVICE_COMPILE__) && __has_builtin(__builtin_amdgcn_fdot2)
    return __builtin_amdgcn_fdot2(wa, xa, ca, false);
#else
    return ca + (float)wa[0] * (float)xa[0] + (float)wa[1] * (float)xa[1];
#endif
}

__device__ __forceinline__ u32 ud4(u32 a, u32 b, u32 c) {   // 4x u8 dot + acc
#if defined(__HIP_DEVICE_COMPILE__) && __has_builtin(__builtin_amdgcn_udot4)
    return __builtin_amdgcn_udot4(a, b, c, false);
#else
    return c + (a & 255u) * (b & 255u) + ((a >> 8) & 255u) * ((b >> 8) & 255u)
             + ((a >> 16) & 255u) * ((b >> 16) & 255u) + (a >> 24) * (b >> 24);
#endif
}

// ---------------------------------------------------------------------------
// pack_wx: merged pack_w (bid<512) + pack_x (bid>=512).
__global__ __launch_bounds__(256) void pack_wx(const float* __restrict__ ntp,
                                               const float* __restrict__ x_all,
                                               ushort* __restrict__ wpk,
                                               ushort* __restrict__ xpk) {
    const int bid = blockIdx.x;
    if (bid < 512) {
        const int g = bid * 256 + threadIdx.x;   // 0..131071
        const int l = g & 63, h = (g >> 6) & 1, i = g >> 7;
        const int row = i * 16 + (l & 15);
        const int t0 = h * 32 + ((l >> 4) << 3);
        const float* src = ntp + row * 64 + t0;
        float4 f0 = *reinterpret_cast<const float4*>(src);
        float4 f1 = *reinterpret_cast<const float4*>(src + 4);
        float v[8] = {f0.x, f0.y, f0.z, f0.w, f1.x, f1.y, f1.z, f1.w};
        u32 o[4];
        #pragma unroll
        for (int q = 0; q < 4; ++q)
            o[q] = f2bf(sigf(v[2 * q])) | (f2bf(sigf(v[2 * q + 1])) << 16);
        uint4 ov; ov.x = o[0]; ov.y = o[1]; ov.z = o[2]; ov.w = o[3];
        *reinterpret_cast<uint4*>(wpk + (size_t)g * 8) = ov;
    } else {
        const int g = (bid - 512) * 256 + threadIdx.x;   // 0..65535
        const int l = g & 63, h = (g >> 6) & 1, j = (g >> 7) & 7, b = g >> 10;
        const int s = j * 16 + (l & 15);
        const int t0 = h * 32 + ((l >> 4) << 3);
        const float* src = x_all + ((size_t)b * LL + s) * TT + t0;
        float4 f0 = *reinterpret_cast<const float4*>(src);
        float4 f1 = *reinterpret_cast<const float4*>(src + 4);
        float v[8] = {f0.x, f0.y, f0.z, f0.w, f1.x, f1.y, f1.z, f1.w};
        u32 o[4];
        #pragma unroll
        for (int q = 0; q < 4; ++q)
            o[q] = f2bf(v[2 * q]) | (f2bf(v[2 * q + 1]) << 16);
        uint4 ov; ov.x = o[0]; ov.y = o[1]; ov.z = o[2]; ov.w = o[3];
        *reinterpret_cast<uint4*>(xpk + (size_t)g * 8) = ov;
    }
}

// ---------------------------------------------------------------------------
// gemm_mfma, layout R4 (u4 npc, 64 MB total):
//   npc byte(b,s,n,m) = b<<20 | (s>>4)<<17 | (s&15)<<13
//                       | ((m>>4) + 8*(n>>6))<<9 | (n&63)<<3 | (m&15)>>1
//   nibble: low = even m, high = odd m. q = round(15*clip01(.)).
__global__ __launch_bounds__(256) void gemm_mfma(const ushort* __restrict__ wpk,
                                                 const ushort* __restrict__ xpk,
                                                 u8* __restrict__ npc) {
    __shared__ __align__(16) u8 stg[4][8192];
    const int b = blockIdx.x >> 4;
    const int nb = blockIdx.x & 15;
    const int wv = threadIdx.x >> 6, l = threadIdx.x & 63;

    uint4 xf[8][2];
    #pragma unroll
    for (int j = 0; j < 8; ++j)
        #pragma unroll
        for (int h = 0; h < 2; ++h)
            xf[j][h] = *reinterpret_cast<const uint4*>(
                xpk + (size_t)(((b * 8 + j) * 2 + h) * 64 + l) * 8);

    const int c = l & 15, r0 = (l >> 4) * 4;
    u8* stw = stg[wv];
    const int khi  = (nb >> 3) * 8;
    const int nlow = (nb & 7) * 8;

    for (int mg2 = 0; mg2 < 2; ++mg2) {
        const int mg = wv * 2 + mg2;
        #pragma unroll
        for (int n_l = 0; n_l < 8; ++n_l) {
            const int i = (nb * 8 + n_l) * 8 + mg;   // tile index
            uint4 a0 = *reinterpret_cast<const uint4*>(wpk + (size_t)((i * 2 + 0) * 64 + l) * 8);
            uint4 a1 = *reinterpret_cast<const uint4*>(wpk + (size_t)((i * 2 + 1) * 64 + l) * 8);
            const f32x4 z = {0.f, 0.f, 0.f, 0.f};
            f32x4 acc[8];
            #pragma unroll
            for (int j = 0; j < 8; ++j)
                acc[j] = __builtin_amdgcn_mfma_f32_16x16x32_bf16(
                    __builtin_bit_cast(s16x8, a0), __builtin_bit_cast(s16x8, xf[j][0]), z, 0, 0, 0);
            #pragma unroll
            for (int j = 0; j < 8; ++j)
                acc[j] = __builtin_amdgcn_mfma_f32_16x16x32_bf16(
                    __builtin_bit_cast(s16x8, a1), __builtin_bit_cast(s16x8, xf[j][1]), acc[j], 0, 0, 0);

            const int sk8 = ((n_l + c) & 7) << 3;   // skewed 8B slot
            #pragma unroll
            for (int j = 0; j < 8; ++j) {
                u32 q0 = (u32)(clip01(acc[j][0]) * 15.f + 0.5f);
                u32 q1 = (u32)(clip01(acc[j][1]) * 15.f + 0.5f);
                u32 q2 = (u32)(clip01(acc[j][2]) * 15.f + 0.5f);
                u32 q3 = (u32)(clip01(acc[j][3]) * 15.f + 0.5f);
                u32 hw = (q0 | (q1 << 4)) | ((q2 | (q3 << 4)) << 8);
                *reinterpret_cast<ushort*>(stw + j * 1024 + c * 64 + sk8 + (r0 >> 1)) = (ushort)hw;
            }
        }
        asm volatile("s_waitcnt lgkmcnt(0)" ::: "memory");
        __builtin_amdgcn_sched_barrier(0);

        // flush: 8 j x 2 rounds of 8-lane 64B full-line coalesced dwordx2
        #pragma unroll
        for (int j = 0; j < 8; ++j) {
            #pragma unroll
            for (int r = 0; r < 2; ++r) {
                const int slot = r * 64 + l;
                const int cc = slot >> 3;        // s-index 0..15
                const int nr = slot & 7;
                uint2 v = *reinterpret_cast<const uint2*>(
                    stw + j * 1024 + cc * 64 + (((nr + cc) & 7) << 3));
                *reinterpret_cast<uint2*>(npc + ((size_t)b << 20) + ((size_t)j << 17)
                    + ((size_t)cc << 13) + ((size_t)(mg + khi) << 9)
                    + ((nlow + nr) << 3)) = v;
            }
        }
        asm volatile("s_waitcnt lgkmcnt(0)" ::: "memory");
        __builtin_amdgcn_sched_barrier(0);
    }
}

// ---------------------------------------------------------------------------
// recur9: 256 threads (4 waves) per batch; thread (n = tid>>1, h = tid&1)
// owns 64 m's of row n: 4 x dwordx2 u4 loads/step (two 256B coalesced runs),
// 16 udot4 on nibble-unpacked words vs pre-packed even/odd prev bytes.
// prev stored directly in packed even/odd u32 form (byte writes at cur time,
// no extra barrier). Raw s_barrier + lgkm-only drain; depth-4 prefetch.
__global__ __launch_bounds__(256, 1) void recur9(const float* __restrict__ x_all,
                                                 const float* __restrict__ tp,
                                                 const u8* __restrict__ npc,
                                                 float* __restrict__ outp) {
    // prev_pk[buf][0..15] = evens: word (mg*2+w) = prev[16mg+8w+{0,2,4,6}]
    // prev_pk[buf][16..31] = odds:  word (mg*2+w) = prev[16mg+8w+{1,3,5,7}]
    __shared__ u32 prev_pk[2][32];
    __shared__ float masks_lds[LL];
    __shared__ float tpc_lds[NN];
    __shared__ float x0_lds[TT];

    const int b = blockIdx.x, tid = threadIdx.x;
    const int n = tid >> 1, h = tid & 1;
    const u8* npcl = npc + ((size_t)b << 20)
                   + ((size_t)((n >> 6) * 8 + h * 4) << 9) + (u32)(n & 63) * 8;

    if (tid < 128) masks_lds[tid] = x_all[(size_t)b * 8192 + tid * 64 + 63];
    else if (tid < 192) x0_lds[tid - 128] = x_all[(size_t)b * 8192 + (tid - 128)];
    __syncthreads();

#define LOADSET(R, T) do { \
        int _t = (T) <= 127 ? (T) : 127; \
        const u8* _p = npcl + ((size_t)(_t >> 4) << 17) + ((size_t)(_t & 15) << 13); \
        R[0] = *reinterpret_cast<const uint2*>(_p); \
        R[1] = *reinterpret_cast<const uint2*>(_p + 512); \
        R[2] = *reinterpret_cast<const uint2*>(_p + 1024); \
        R[3] = *reinterpret_cast<const uint2*>(_p + 1536); \
        asm volatile("" ::: "memory"); \
    } while (0)

    uint2 nA[4], nB[4], nC[4], nD[4];
    LOADSET(nA, 1); LOADSET(nB, 2); LOADSET(nC, 3); LOADSET(nD, 4);

    // tpc (exact f32): thread tid < 128 computes row tid; hides prefetch
    float out_r = 0.f;
    if (tid < 128) {
        float a = 0.f;
        #pragma unroll
        for (int t4 = 0; t4 < 16; ++t4) {
            float4 xv = *reinterpret_cast<const float4*>(x0_lds + t4 * 4);
            float4 w0 = *reinterpret_cast<const float4*>(tp + tid * 64 + t4 * 4);
            a += sigf(w0.x) * xv.x; a += sigf(w0.y) * xv.y;
            a += sigf(w0.z) * xv.z; a += sigf(w0.w) * xv.w;
        }
        tpc_lds[tid] = a;
        if (tid == 0) out_r = a;            // out0 = tpc[0]
    }
    asm volatile("s_waitcnt lgkmcnt(0)" ::: "memory");
    __builtin_amdgcn_s_barrier();
    __builtin_amdgcn_sched_barrier(0);

    // packed-prev byte-write helper index for row n (h==0 threads)
    const int wr_idx  = ((n >> 4) << 1) + ((n >> 3) & 1) + ((n & 1) << 4);
    const int wr_byte = (n & 7) >> 1;

    // ---- step 1: cur1 = clip01(npc1 . tpc), tpc f32 (unclipped range) ----
    {
        float sf = 0.f;
        #pragma unroll
        for (int kk = 0; kk < 4; ++kk) {
            const int base_m = (4 * h + kk) * 16;
            u32 wlo = nA[kk].x, whi = nA[kk].y;
            #pragma unroll
            for (int by = 0; by < 4; ++by) {
                u32 b0 = (wlo >> (8 * by)) & 0xFFu;
                sf += (float)(b0 & 15u) * tpc_lds[base_m + 2 * by];
                sf += (float)(b0 >> 4)  * tpc_lds[base_m + 2 * by + 1];
                u32 b1 = (whi >> (8 * by)) & 0xFFu;
                sf += (float)(b1 & 15u) * tpc_lds[base_m + 8 + 2 * by];
                sf += (float)(b1 >> 4)  * tpc_lds[base_m + 8 + 2 * by + 1];
            }
        }
        float tot = sf + __shfl_xor(sf, 1);
        float c0 = clip01(tot * (1.f / 15.f));
        if (h == 0) {
            u32 q8 = (u32)(c0 * 255.f + 0.5f);
            ((u8*)&prev_pk[0][wr_idx])[wr_byte] = (u8)q8;
        }
        if (tid == 0) {
            float mk = masks_lds[1];
            out_r = out_r * mk + c0 * (1.f - mk);
        }
        asm volatile("s_waitcnt lgkmcnt(0)" ::: "memory");
        __builtin_amdgcn_s_barrier();
        __builtin_amdgcn_sched_barrier(0);
    }
    LOADSET(nA, 5);

    int p = 0;

#define STEP(R, S) do { \
        uint4 pe0 = *reinterpret_cast<const uint4*>(&prev_pk[p][8 * h]); \
        uint4 pe1 = *reinterpret_cast<const uint4*>(&prev_pk[p][8 * h + 4]); \
        uint4 po0 = *reinterpret_cast<const uint4*>(&prev_pk[p][16 + 8 * h]); \
        uint4 po1 = *reinterpret_cast<const uint4*>(&prev_pk[p][16 + 8 * h + 4]); \
        u32 PE[8] = {pe0.x, pe0.y, pe0.z, pe0.w, pe1.x, pe1.y, pe1.z, pe1.w}; \
        u32 PO[8] = {po0.x, po0.y, po0.z, po0.w, po1.x, po1.y, po1.z, po1.w}; \
        float mk = masks_lds[(S)]; \
        u32 ae = 0, ao = 0; \
        _Pragma("unroll") \
        for (int _kk = 0; _kk < 4; ++_kk) { \
            u32 _w0 = R[_kk].x, _w1 = R[_kk].y; \
            ae = ud4(_w0 & 0x0F0F0F0Fu, PE[2 * _kk], ae); \
            ao = ud4((_w0 >> 4) & 0x0F0F0F0Fu, PO[2 * _kk], ao); \
            ae = ud4(_w1 & 0x0F0F0F0Fu, PE[2 * _kk + 1], ae); \
            ao = ud4((_w1 >> 4) & 0x0F0F0F0Fu, PO[2 * _kk + 1], ao); \
        } \
        float sf = (float)(ae + ao); \
        float tot = sf + __shfl_xor(sf, 1); \
        float c0 = fminf(tot * (1.f / 3825.f), 1.f); \
        if (h == 0) { \
            u32 q8 = (u32)(c0 * 255.f + 0.5f); \
            ((u8*)&prev_pk[p ^ 1][wr_idx])[wr_byte] = (u8)q8; \
        } \
        if (tid == 0) out_r = out_r * mk + c0 * (1.f - mk); \
        asm volatile("s_waitcnt lgkmcnt(0)" ::: "memory"); \
        __builtin_amdgcn_s_barrier(); \
        __builtin_amdgcn_sched_barrier(0); \
        p ^= 1; \
    } while (0)

    // steps 2..125: 31 iterations x 4 steps, rotation B,C,D,A; loads 4 ahead
    for (int g = 0; g < 31; ++g) {
        const int s = 2 + 4 * g;
        STEP(nB, s);     LOADSET(nB, s + 4);
        STEP(nC, s + 1); LOADSET(nC, s + 5);
        STEP(nD, s + 2); LOADSET(nD, s + 6);
        STEP(nA, s + 3); LOADSET(nA, s + 7);
    }
    // tail: steps 126 (nB), 127 (nC); nD/nA hold dead clamped loads
    STEP(nB, 126);
    STEP(nC, 127);

#undef STEP
#undef LOADSET

    if (tid == 0) outp[b] = out_r;
}

// ---------------------------------------------------------------------------
// Fallback (known-passing round-2 kernel): fused recurrence, 2 MB ws.
__global__ __launch_bounds__(256) void sig_transpose(const float* __restrict__ ntp,
                                                     u32* __restrict__ out) {
    __shared__ float lds[64 * 65];
    const int nm0 = blockIdx.x * 64;
    const int tid = threadIdx.x;
    #pragma unroll
    for (int it = 0; it < 16; ++it) {
        int idx = it * 256 + tid;
        int r = idx >> 6, c = idx & 63;
        lds[r * 65 + c] = sigf(ntp[(nm0 + r) * 64 + c]);
    }
    __syncthreads();
    #pragma unroll
    for (int it = 0; it < 8; ++it) {
        int o = it * 256 + tid;
        int tpi = o >> 6, r = o & 63;
        f16x2 h;
        h[0] = (f16)lds[r * 65 + 2 * tpi];
        h[1] = (f16)lds[r * 65 + 2 * tpi + 1];
        out[tpi * NM + nm0 + r] = __builtin_bit_cast(u32, h);
    }
}

__global__ __launch_bounds__(1024) void grammar_fused(
    const float* __restrict__ x_all,
    const float* __restrict__ tp,
    const u32*  __restrict__ ntpT2,
    float* __restrict__ outp) {
    __shared__ float x_lds[LL * TT];
    __shared__ float prevbuf[2][NN];
    __shared__ u32 x2_lds[2][32];

    const int b = blockIdx.x;
    const int tid = threadIdx.x;
    const int lane16 = tid & 15;
    const int g = tid >> 4;
    const int mbase = lane16 * 8;

    const float* xb = x_all + b * (LL * TT);
    #pragma unroll
    for (int it = 0; it < 8; ++it) {
        int idx = it * 1024 + tid;
        x_lds[idx] = xb[idx];
    }
    __syncthreads();

    if (tid < NN) {
        float acc = 0.f;
        #pragma unroll 8
        for (int t = 0; t < TT; ++t)
            acc += sigf(tp[tid * TT + t]) * x_lds[t];
        prevbuf[0][tid] = acc;
    }
    __syncthreads();
    float out_r = 0.f;
    if (tid == 0) out_r = prevbuf[0][0];

    int p = 0;
    for (int i0 = 1; i0 < LL; i0 += 2) {
        const int ns = (LL - i0) >= 2 ? 2 : 1;
        if (tid < 64) {
            int s = tid >> 5, tpi = tid & 31;
            f16x2 h;
            if (s < ns) {
                h[0] = (f16)x_lds[(i0 + s) * TT + 2 * tpi];
                h[1] = (f16)x_lds[(i0 + s) * TT + 2 * tpi + 1];
            } else {
                h[0] = (f16)0.f; h[1] = (f16)0.f;
            }
            x2_lds[s][tpi] = __builtin_bit_cast(u32, h);
        }
        __syncthreads();

        float acc[2][2][8];
        #pragma unroll
        for (int k = 0; k < 2; ++k)
            #pragma unroll
            for (int s = 0; s < 2; ++s)
                #pragma unroll
                for (int j = 0; j < 8; ++j) acc[k][s][j] = 0.f;

        #pragma unroll 2
        for (int tpi = 0; tpi < 32; ++tpi) {
            f16x2 xv0 = __builtin_bit_cast(f16x2, x2_lds[0][tpi]);
            f16x2 xv1 = __builtin_bit_cast(f16x2, x2_lds[1][tpi]);
            const u32* base = ntpT2 + tpi * NM + 8 * tid;
            #pragma unroll
            for (int k = 0; k < 2; ++k) {
                uint4 w0 = *reinterpret_cast<const uint4*>(base + 8192 * k);
                uint4 w1 = *reinterpret_cast<const uint4*>(base + 8192 * k + 4);
                u32 wv[8] = {w0.x, w0.y, w0.z, w0.w, w1.x, w1.y, w1.z, w1.w};
                #pragma unroll
                for (int j = 0; j < 8; ++j) {
                    f16x2 w = __builtin_bit_cast(f16x2, wv[j]);
                    acc[k][0][j] = fdot2f(w, xv0, acc[k][0][j]);
                    acc[k][1][j] = fdot2f(w, xv1, acc[k][1][j]);
                }
            }
        }

        for (int s = 0; s < ns; ++s) {
            float4 pv0 = *reinterpret_cast<const float4*>(&prevbuf[p][mbase]);
            float4 pv1 = *reinterpret_cast<const float4*>(&prevbuf[p][mbase + 4]);
            float pvv[8] = {pv0.x, pv0.y, pv0.z, pv0.w, pv1.x, pv1.y, pv1.z, pv1.w};
            #pragma unroll
            for (int k = 0; k < 2; ++k) {
                float part = 0.f;
                #pragma unroll
                for (int j = 0; j < 8; ++j) {
                    float npcv = clip01(acc[k][s][j]);
                    part += npcv * pvv[j];
                }
                part += __shfl_xor(part, 1);
                part += __shfl_xor(part, 2);
                part += __shfl_xor(part, 4);
                part += __shfl_xor(part, 8);
                if (lane16 == 0) {
                    float c = clip01(part);
                    prevbuf[p ^ 1][g + 64 * k] = c;
                    if (tid == 0 && k == 0) {
                        float mask = x_lds[(i0 + s) * TT + 63];
                        out_r = out_r * mask + c * (1.f - mask);
                    }
                }
            }
            p ^= 1;
            __syncthreads();
        }
    }

    if (tid == 0) outp[b] = out_r;
}

// ---------------------------------------------------------------------------
extern "C" void kernel_launch(void* const* d_in, const int* in_sizes, int n_in,
                              void* d_out, int out_size, void* d_ws, size_t ws_size,
                              hipStream_t stream) {
    const float* input_tensor = (const float*)d_in[0];   // [64][128][64]
    const float* term_prod    = (const float*)d_in[1];   // [128][64]
    const float* nonterm_prod = (const float*)d_in[2];   // [128][128][64]
    float* outp = (float*)d_out;                         // [64]

    const size_t MB = 1024 * 1024;
    const size_t NPC_BYTES = 64 * MB;    // layout R4 (u4)
    const size_t WPK_BYTES = 2 * MB;     // bf16 A-frags
    const size_t XPK_BYTES = 1 * MB;     // bf16 B-frags

    if (ws_size >= NPC_BYTES + WPK_BYTES + XPK_BYTES + MB) {
        u8* npcbuf  = (u8*)d_ws;
        ushort* wpk = (ushort*)((char*)d_ws + NPC_BYTES);
        ushort* xpk = (ushort*)((char*)d_ws + NPC_BYTES + WPK_BYTES);
        pack_wx<<<768, 256, 0, stream>>>(nonterm_prod, input_tensor, wpk, xpk);
        gemm_mfma<<<1024, 256, 0, stream>>>(wpk, xpk, npcbuf);
        recur9<<<BB, 256, 0, stream>>>(input_tensor, term_prod, npcbuf, outp);
    } else {
        u32* ntpT2 = (u32*)d_ws;
        sig_transpose<<<256, 256, 0, stream>>>(nonterm_prod, ntpT2);
        grammar_fused<<<BB, 1024, 0, stream>>>(input_tensor, term_prod, ntpT2, outp);
    }
}